// Round 2
// baseline (698.207 us; speedup 1.0000x reference)
//
#include <hip/hip_runtime.h>
#include <hip/hip_cooperative_groups.h>

namespace cg = cooperative_groups;

// Problem constants (from reference setup_inputs)
#define B_ 64
#define C_ 256
#define T_ 2048
#define EPS_ 1e-4f
#define NPC ((float)(B_ * T_))   // elements per channel = 131072

#define T4 (T_ / 4)              // 512 vec4 per row

// Fused-kernel geometry: 1024 blocks x 256 threads = 4 blocks/CU (co-resident)
#define NBLK 1024
#define SPLITS 4                 // stats splits (phase A): block (c,s), s in [0,4)
#define BPB (B_ / SPLITS)        // 16 batch rows per stats block
#define BCHUNK 32                // batch rows per norm thread (phase C)

typedef float f4 __attribute__((ext_vector_type(4)));

// ---------------------------------------------------------------------------
// Single cooperative kernel: stats -> grid.sync -> finalize+transpose ->
// grid.sync -> normalize. Eliminates 2 dispatches + gaps vs the 3-kernel path.
//   ws layout: partials [2][SPLITS][C] | scale [C][T] | shift [C][T]
// ---------------------------------------------------------------------------
__global__ __launch_bounds__(256, 4) void bntt_fused(const float* __restrict__ x,
                                                     const float* __restrict__ gamma,
                                                     const float* __restrict__ beta,
                                                     float* __restrict__ out,
                                                     float* __restrict__ ws) {
    float* partials = ws;                          // 2*SPLITS*C_ floats
    float* scale    = ws + 2 * SPLITS * C_;        // C_*T_ floats
    float* shift    = scale + (size_t)C_ * T_;     // C_*T_ floats

    const int tid = threadIdx.x;
    const int bid = blockIdx.x;
    cg::grid_group grid = cg::this_grid();

    // ---- Phase A: per-channel partial sum & sumsq ----
    // block (c,s): c = bid & 255, s = bid >> 8 in [0,4); reads 16 rows of 8 KiB.
    {
        const int c  = bid & (C_ - 1);
        const int s  = bid >> 8;
        const int b0 = s * BPB;
        float sum = 0.0f, sumsq = 0.0f;
        #pragma unroll 4
        for (int b = 0; b < BPB; ++b) {
            const f4* p = (const f4*)(x + (size_t)(b0 + b) * (C_ * T_) + (size_t)c * T_);
            #pragma unroll
            for (int i = 0; i < T4 / 256; ++i) {
                f4 v = p[tid + i * 256];
                sum   += v.x + v.y + v.z + v.w;
                sumsq += v.x * v.x + v.y * v.y + v.z * v.z + v.w * v.w;
            }
        }
        #pragma unroll
        for (int off = 32; off > 0; off >>= 1) {
            sum   += __shfl_down(sum, off);
            sumsq += __shfl_down(sumsq, off);
        }
        __shared__ float ls[4], lss[4];
        const int wave = tid >> 6, lane = tid & 63;
        if (lane == 0) { ls[wave] = sum; lss[wave] = sumsq; }
        __syncthreads();
        if (tid == 0) {
            partials[s * C_ + c]               = ls[0] + ls[1] + ls[2] + ls[3];
            partials[SPLITS * C_ + s * C_ + c] = lss[0] + lss[1] + lss[2] + lss[3];
        }
    }
    __threadfence();   // cross-XCD visibility of partials
    grid.sync();

    // ---- Phase B: finalize stats + transpose gamma/beta -> scale/shift [C][T]
    // 512 tiles of 32x32; blocks 0..511 each do one tile with 256 threads
    // (4 rows per thread). Blocks 512..1023 fall through to the sync.
    __shared__ float tg[32][33];
    __shared__ float tb[32][33];
    __shared__ float smean[32], sistd[32];
    if (bid < 512) {
        const int c0  = (bid & 7) * 32;      // 8 channel-tiles
        const int t0  = (bid >> 3) * 32;     // 64 time-tiles
        const int tx  = tid & 31;
        const int ty4 = tid >> 5;            // 0..7
        if (tid < 32) {
            const int c = c0 + tid;
            float S = 0.0f, SS = 0.0f;
            #pragma unroll
            for (int s = 0; s < SPLITS; ++s) {
                S  += partials[s * C_ + c];
                SS += partials[SPLITS * C_ + s * C_ + c];
            }
            float mean = S / NPC;
            smean[tid] = mean;
            sistd[tid] = rsqrtf(SS / NPC - mean * mean + EPS_);
        }
        #pragma unroll
        for (int r = 0; r < 4; ++r) {
            const int ty = ty4 + r * 8;
            tg[ty][tx] = gamma[(size_t)(t0 + ty) * C_ + (c0 + tx)];
            tb[ty][tx] = beta [(size_t)(t0 + ty) * C_ + (c0 + tx)];
        }
        __syncthreads();
        #pragma unroll
        for (int r = 0; r < 4; ++r) {
            const int ty  = ty4 + r * 8;
            const float mean = smean[ty];
            const float istd = sistd[ty];
            const float sc = tg[tx][ty] * istd;
            scale[(size_t)(c0 + ty) * T_ + (t0 + tx)] = sc;
            shift[(size_t)(c0 + ty) * T_ + (t0 + tx)] = fmaf(-mean, sc, tb[tx][ty]);
        }
    }
    __threadfence();   // cross-XCD visibility of scale/shift
    grid.sync();

    // ---- Phase C: normalize. Thread owns one (c,t4) vec4; streams BCHUNK rows.
    {
        const int p  = (bid & 511) * 256 + tid;   // (c,t4) index
        const int c  = p >> 9;
        const int t4 = p & (T4 - 1);
        const int b0 = (bid >> 9) * BCHUNK;

        const f4 sc = ((const f4*)scale)[(size_t)c * T4 + t4];
        const f4 sh = ((const f4*)shift)[(size_t)c * T4 + t4];

        size_t idx = (size_t)(b0 * C_ + c) * T4 + t4;
        const size_t step = (size_t)C_ * T4;      // one batch row
        #pragma unroll 4
        for (int b = 0; b < BCHUNK; ++b) {
            f4 xv = ((const f4*)x)[idx];
            f4 o;
            o.x = fmaf(xv.x, sc.x, sh.x);
            o.y = fmaf(xv.y, sc.y, sh.y);
            o.z = fmaf(xv.z, sc.z, sh.z);
            o.w = fmaf(xv.w, sc.w, sh.w);
            __builtin_nontemporal_store(o, &((f4*)out)[idx]);
            idx += step;
        }
    }
}

// ---------------------------------------------------------------------------
// Fallback path (ws too small for scale/shift): 2 plain dispatches.
// ---------------------------------------------------------------------------
__global__ __launch_bounds__(256) void bntt_stats(const float* __restrict__ x,
                                                  float* __restrict__ partials) {
    const int c   = blockIdx.x & (C_ - 1);
    const int s   = blockIdx.x >> 8;
    const int tid = threadIdx.x;

    float sum = 0.0f, sumsq = 0.0f;
    const int b0 = s * BPB;
    #pragma unroll 4
    for (int b = 0; b < BPB; ++b) {
        const f4* p = (const f4*)(x + (size_t)(b0 + b) * (C_ * T_) + (size_t)c * T_);
        #pragma unroll
        for (int i = 0; i < T4 / 256; ++i) {
            f4 v = p[tid + i * 256];
            sum   += v.x + v.y + v.z + v.w;
            sumsq += v.x * v.x + v.y * v.y + v.z * v.z + v.w * v.w;
        }
    }
    #pragma unroll
    for (int off = 32; off > 0; off >>= 1) {
        sum   += __shfl_down(sum, off);
        sumsq += __shfl_down(sumsq, off);
    }
    __shared__ float ls[4], lss[4];
    const int wave = tid >> 6, lane = tid & 63;
    if (lane == 0) { ls[wave] = sum; lss[wave] = sumsq; }
    __syncthreads();
    if (tid == 0) {
        partials[s * C_ + c]               = ls[0] + ls[1] + ls[2] + ls[3];
        partials[SPLITS * C_ + s * C_ + c] = lss[0] + lss[1] + lss[2] + lss[3];
    }
}

__global__ __launch_bounds__(256) void bntt_norm_fb(const float* __restrict__ x,
                                                    const float* __restrict__ gamma,
                                                    const float* __restrict__ beta,
                                                    const float* __restrict__ partials,
                                                    float* __restrict__ out) {
    const int p   = (blockIdx.x & 511) * 256 + threadIdx.x;
    const int c   = p >> 9;
    const int t4  = p & (T4 - 1);
    const int t   = t4 * 4;
    const int b0  = (blockIdx.x >> 9) * BCHUNK;

    float S = 0.0f, SS = 0.0f;
    #pragma unroll
    for (int s = 0; s < SPLITS; ++s) {
        S  += partials[s * C_ + c];
        SS += partials[SPLITS * C_ + s * C_ + c];
    }
    const float mean = S / NPC;
    const float istd = rsqrtf(SS / NPC - mean * mean + EPS_);

    f4 sc, sh;
    #pragma unroll
    for (int j = 0; j < 4; ++j) {
        float g  = gamma[(size_t)(t + j) * C_ + c];
        float bb = beta [(size_t)(t + j) * C_ + c];
        float s1 = g * istd;
        ((float*)&sc)[j] = s1;
        ((float*)&sh)[j] = fmaf(-mean, s1, bb);
    }
    size_t idx = (size_t)(b0 * C_ + c) * T4 + t4;
    const size_t step = (size_t)C_ * T4;
    #pragma unroll 4
    for (int b = 0; b < BCHUNK; ++b) {
        f4 xv = ((const f4*)x)[idx];
        f4 o;
        o.x = fmaf(xv.x, sc.x, sh.x);
        o.y = fmaf(xv.y, sc.y, sh.y);
        o.z = fmaf(xv.z, sc.z, sh.z);
        o.w = fmaf(xv.w, sc.w, sh.w);
        __builtin_nontemporal_store(o, &((f4*)out)[idx]);
        idx += step;
    }
}

extern "C" void kernel_launch(void* const* d_in, const int* in_sizes, int n_in,
                              void* d_out, int out_size, void* d_ws, size_t ws_size,
                              hipStream_t stream) {
    const float* x     = (const float*)d_in[0];
    const float* gamma = (const float*)d_in[1];
    const float* beta  = (const float*)d_in[2];
    float* out = (float*)d_out;
    float* wsf = (float*)d_ws;

    const size_t need = (2 * SPLITS * C_ + 2 * (size_t)C_ * T_) * sizeof(float);

    if (ws_size >= need) {
        void* args[] = { (void*)&x, (void*)&gamma, (void*)&beta, (void*)&out, (void*)&wsf };
        hipLaunchCooperativeKernel((void*)bntt_fused, dim3(NBLK), dim3(256),
                                   args, 0, stream);
    } else {
        // partials-only fallback: 4 KB of ws
        bntt_stats<<<C_ * SPLITS, 256, 0, stream>>>(x, wsf);
        const int ngrid = (C_ * T4 / 256) * (B_ / BCHUNK);
        bntt_norm_fb<<<ngrid, 256, 0, stream>>>(x, gamma, beta, wsf, out);
    }
}

// Round 3
// 251.555 us; speedup vs baseline: 2.7756x; 2.7756x over previous
//
#include <hip/hip_runtime.h>

// Problem constants (from reference setup_inputs)
#define B_ 64
#define C_ 256
#define T_ 2048
#define EPS_ 1e-4f
#define NPC ((float)(B_ * T_))   // elements per channel = 131072

#define SPLITS 8
#define BPB (B_ / SPLITS)        // 8 batch rows per stats block
#define T4 (T_ / 4)              // 512 vec4 per row

// Norm kernel tiling: block = 16 channels x 16 t4 (=64 t), 32 batch rows
#define CTILE 16
#define T4TILE 16
#define BCHUNK 32

typedef float f4 __attribute__((ext_vector_type(4)));

// ---------------------------------------------------------------------------
// Kernel 1: per-channel partial sum & sumsq. Grid = C_*SPLITS = 2048 blocks
// of 256 (8 blocks/CU -> 32 waves/CU). No atomics, no init: block (c,s)
// writes partials to a disjoint slot.  partials layout: [2][SPLITS][C]
// ---------------------------------------------------------------------------
__global__ __launch_bounds__(256) void bntt_stats(const float* __restrict__ x,
                                                  float* __restrict__ partials) {
    const int c   = blockIdx.x & (C_ - 1);
    const int s   = blockIdx.x >> 8;
    const int tid = threadIdx.x;

    float sum = 0.0f, sumsq = 0.0f;
    const int b0 = s * BPB;
    #pragma unroll
    for (int b = 0; b < BPB; ++b) {
        const f4* p = (const f4*)(x + (size_t)(b0 + b) * (C_ * T_) + (size_t)c * T_);
        #pragma unroll
        for (int i = 0; i < T4 / 256; ++i) {
            f4 v = p[tid + i * 256];
            sum   += v.x + v.y + v.z + v.w;
            sumsq += v.x * v.x + v.y * v.y + v.z * v.z + v.w * v.w;
        }
    }
    #pragma unroll
    for (int off = 32; off > 0; off >>= 1) {
        sum   += __shfl_down(sum, off);
        sumsq += __shfl_down(sumsq, off);
    }
    __shared__ float ls[4], lss[4];
    const int wave = tid >> 6, lane = tid & 63;
    if (lane == 0) { ls[wave] = sum; lss[wave] = sumsq; }
    __syncthreads();
    if (tid == 0) {
        partials[s * C_ + c]               = ls[0] + ls[1] + ls[2] + ls[3];
        partials[SPLITS * C_ + s * C_ + c] = lss[0] + lss[1] + lss[2] + lss[3];
    }
}

// ---------------------------------------------------------------------------
// Kernel 2: finalize + normalize, fused (replaces prep + norm).
// Grid = 1024 blocks x 256 threads:
//   tile id = bid & 511  ->  c0 = (tile>>5)*16, t4base = (tile&31)*16
//   b-half  = bid >> 9   ->  b0 = half * 32
// Per block:
//   - threads 0..15 reduce the 8-split partials for the 16 channels -> LDS
//   - stage gamma/beta [64 t x 16 c] slice into LDS, fully coalesced
//     (lanes span 16 consecutive channels = 64B lines fully used)
//   - each thread owns one (c, t4): builds scale/shift f4 in registers once,
//     then streams 32 batch rows with f4 loads + non-temporal stores.
// x coalescing: consecutive lanes = consecutive t4 (16 x 16B = 256B segments,
// all 64B lines fully used).
// ---------------------------------------------------------------------------
__global__ __launch_bounds__(256) void bntt_norm(const float* __restrict__ x,
                                                 const float* __restrict__ gamma,
                                                 const float* __restrict__ beta,
                                                 const float* __restrict__ partials,
                                                 float* __restrict__ out) {
    __shared__ float sg[64][17];   // gamma slice [t_local][c_local], padded
    __shared__ float sb[64][17];   // beta  slice
    __shared__ float smean[CTILE], sistd[CTILE];

    const int tid    = threadIdx.x;
    const int tile   = blockIdx.x & 511;
    const int c0     = (tile >> 5) * CTILE;      // 16 channel-tiles
    const int t4base = (tile & 31) * T4TILE;     // 32 t4-tiles
    const int b0     = (blockIdx.x >> 9) * BCHUNK;

    // finalize stats for this block's 16 channels
    if (tid < CTILE) {
        const int c = c0 + tid;
        float S = 0.0f, SS = 0.0f;
        #pragma unroll
        for (int s = 0; s < SPLITS; ++s) {
            S  += partials[s * C_ + c];
            SS += partials[SPLITS * C_ + s * C_ + c];
        }
        const float mean = S / NPC;
        smean[tid] = mean;
        sistd[tid] = rsqrtf(SS / NPC - mean * mean + EPS_);
    }

    // stage gamma/beta slice: rows t = t4base*4 .. +63, cols c0 .. c0+15
    {
        const int cl = tid & 15;
        const int tl0 = tid >> 4;                // 0..15
        const int tbase = t4base * 4;
        #pragma unroll
        for (int it = 0; it < 4; ++it) {
            const int tl = tl0 + it * 16;        // 0..63
            const size_t gi = (size_t)(tbase + tl) * C_ + (c0 + cl);
            sg[tl][cl] = gamma[gi];
            sb[tl][cl] = beta[gi];
        }
    }
    __syncthreads();

    // per-thread affine: thread = (ci, t4i)
    const int t4i = tid & 15;
    const int ci  = tid >> 4;
    const float mean = smean[ci];
    const float istd = sistd[ci];
    f4 sc, sh;
    #pragma unroll
    for (int j = 0; j < 4; ++j) {
        const int tl = t4i * 4 + j;
        const float s1 = sg[tl][ci] * istd;
        ((float*)&sc)[j] = s1;
        ((float*)&sh)[j] = fmaf(-mean, s1, sb[tl][ci]);
    }

    // stream 32 batch rows
    size_t idx = ((size_t)b0 * C_ + (c0 + ci)) * T4 + (t4base + t4i);
    const size_t step = (size_t)C_ * T4;         // one batch row
    #pragma unroll 4
    for (int b = 0; b < BCHUNK; ++b) {
        f4 xv = ((const f4*)x)[idx];
        f4 o;
        o.x = fmaf(xv.x, sc.x, sh.x);
        o.y = fmaf(xv.y, sc.y, sh.y);
        o.z = fmaf(xv.z, sc.z, sh.z);
        o.w = fmaf(xv.w, sc.w, sh.w);
        __builtin_nontemporal_store(o, &((f4*)out)[idx]);
        idx += step;
    }
}

extern "C" void kernel_launch(void* const* d_in, const int* in_sizes, int n_in,
                              void* d_out, int out_size, void* d_ws, size_t ws_size,
                              hipStream_t stream) {
    const float* x     = (const float*)d_in[0];
    const float* gamma = (const float*)d_in[1];
    const float* beta  = (const float*)d_in[2];
    float* out = (float*)d_out;
    float* partials = (float*)d_ws;              // 2*SPLITS*C_ = 4096 floats (16 KB)

    bntt_stats<<<C_ * SPLITS, 256, 0, stream>>>(x, partials);

    const int ngrid = (C_ / CTILE) * (T4 / T4TILE) * (B_ / BCHUNK);  // 512*2 = 1024
    bntt_norm<<<ngrid, 256, 0, stream>>>(x, gamma, beta, partials, out);
}